// Round 1
// baseline (650.408 us; speedup 1.0000x reference)
//
#include <hip/hip_runtime.h>
#include <math.h>

#define B_ 2
#define T_ 2048
#define D_ 512
#define H_ 8
#define HD_ 64
#define NG_ (B_*H_)
#define EPS_ 1e-5f

// ---------------- Kernel 1: fused QKV projection ----------------
// C[n,o] = sum_i x[n,i] * W[o,i] + b[o]   (x @ W^T + b)
// scattered to dst[b*H+h][t][d] with n=b*T+t, o=h*64+d.
// blockIdx.z selects Q/K/V. 64x64 output tile per block, 256 threads, 4x4/thread.
__global__ __launch_bounds__(256) void proj_kernel(
    const float* __restrict__ x,
    const float* __restrict__ Wq, const float* __restrict__ Wk, const float* __restrict__ Wv,
    const float* __restrict__ bq, const float* __restrict__ bk, const float* __restrict__ bv,
    float* __restrict__ Qo, float* __restrict__ Ko, float* __restrict__ Vo)
{
    const float* W; const float* bias; float* dst;
    if (blockIdx.z == 0)      { W = Wq; bias = bq; dst = Qo; }
    else if (blockIdx.z == 1) { W = Wk; bias = bk; dst = Ko; }
    else                      { W = Wv; bias = bv; dst = Vo; }

    // transposed tiles: [i][n] so the inner loop reads contiguous float4
    __shared__ __align__(16) float As[16][68];
    __shared__ __align__(16) float Bs[16][68];

    const int tid = threadIdx.x;
    const int n0 = blockIdx.x * 64;
    const int o0 = blockIdx.y * 64;
    const int tx = tid & 15, ty = tid >> 4;
    const int lr = tid >> 2;         // 0..63 tile row
    const int lc = (tid & 3) * 4;    // 0,4,8,12 k-col

    float acc[4][4] = {};

    for (int kk = 0; kk < D_; kk += 16) {
        float4 av  = *(const float4*)&x[(size_t)(n0 + lr) * D_ + kk + lc];
        float4 bv4 = *(const float4*)&W[(size_t)(o0 + lr) * D_ + kk + lc];
        __syncthreads();   // previous iteration's reads complete
        As[lc+0][lr] = av.x;  As[lc+1][lr] = av.y;  As[lc+2][lr] = av.z;  As[lc+3][lr] = av.w;
        Bs[lc+0][lr] = bv4.x; Bs[lc+1][lr] = bv4.y; Bs[lc+2][lr] = bv4.z; Bs[lc+3][lr] = bv4.w;
        __syncthreads();
        #pragma unroll
        for (int i = 0; i < 16; i++) {
            float4 a = *(const float4*)&As[i][ty * 4];
            float4 b = *(const float4*)&Bs[i][tx * 4];
            float ar[4] = {a.x, a.y, a.z, a.w};
            float br[4] = {b.x, b.y, b.z, b.w};
            #pragma unroll
            for (int r = 0; r < 4; r++)
                #pragma unroll
                for (int c = 0; c < 4; c++)
                    acc[r][c] += ar[r] * br[c];
        }
    }

    const int h = o0 >> 6;                 // whole block is one head
    #pragma unroll
    for (int r = 0; r < 4; r++) {
        int n = n0 + ty * 4 + r;
        int b = n >> 11, t = n & (T_ - 1);
        int dcol = tx * 4;
        float4 v;
        v.x = acc[r][0] + bias[o0 + dcol + 0];
        v.y = acc[r][1] + bias[o0 + dcol + 1];
        v.z = acc[r][2] + bias[o0 + dcol + 2];
        v.w = acc[r][3] + bias[o0 + dcol + 3];
        *(float4*)&dst[(((size_t)(b * H_ + h) * T_ + t) * HD_) + dcol] = v;
    }
}

// ---------------- Kernel 2: windowed retention ----------------
// per (g = b*H+h, 64-query tile): O[q,d] = sum_k gamma^(q-k) (Q.K^T)[q,k] V[k,d]
// window truncated where gamma^dist < ~1e-15 (dist bound from runtime gamma).
// Also accumulates group sum / sumsq for GroupNorm.
__global__ __launch_bounds__(256) void retention_kernel(
    const float* __restrict__ Q, const float* __restrict__ K, const float* __restrict__ V,
    const float* __restrict__ gamma_p,
    float* __restrict__ out,     // [B,T,D] pre-norm
    float* __restrict__ stats)   // [16 sums][16 sumsq]
{
    __shared__ __align__(16) float Qs[64][68];  // [d][q]
    __shared__ __align__(16) float Ks[64][68];  // [d][k], reused as Ss[k][q]
    __shared__ __align__(16) float Vs[64][68];  // [k][d]

    const int tid = threadIdx.x;
    const int tx = tid & 15, ty = tid >> 4;
    const int qt = blockIdx.x;
    const int g  = blockIdx.y;          // b*H + h
    const int q0 = qt * 64;

    const float gamma = gamma_p[0];
    const float lg = logf(gamma);
    int kt0 = 0;
    if (lg < -1e-6f) {
        int maxd = (int)(-34.0f / lg) + 64;  // gamma^maxd < ~2e-15
        kt0 = qt - (maxd >> 6);
        if (kt0 < 0) kt0 = 0;
    }

    const int lr = tid >> 2;
    const int lc = (tid & 3) * 4;

    // load Q tile transposed: Qs[d][q]
    #pragma unroll
    for (int j = 0; j < 4; j++) {
        int dcol = lc + j * 16;
        float4 qv = *(const float4*)&Q[((size_t)g * T_ + q0 + lr) * HD_ + dcol];
        Qs[dcol+0][lr] = qv.x; Qs[dcol+1][lr] = qv.y; Qs[dcol+2][lr] = qv.z; Qs[dcol+3][lr] = qv.w;
    }

    float o_acc[4][4] = {};

    for (int kt = kt0; kt <= qt; kt++) {
        const int k0 = kt * 64;
        float4 kv[4], vv[4];
        #pragma unroll
        for (int j = 0; j < 4; j++) {
            int dcol = lc + j * 16;
            kv[j] = *(const float4*)&K[((size_t)g * T_ + k0 + lr) * HD_ + dcol];
            vv[j] = *(const float4*)&V[((size_t)g * T_ + k0 + lr) * HD_ + dcol];
        }
        __syncthreads();   // prior-iter LDS reads done (also publishes Qs on first iter)
        #pragma unroll
        for (int j = 0; j < 4; j++) {
            int dcol = lc + j * 16;
            Ks[dcol+0][lr] = kv[j].x; Ks[dcol+1][lr] = kv[j].y;
            Ks[dcol+2][lr] = kv[j].z; Ks[dcol+3][lr] = kv[j].w;
            *(float4*)&Vs[lr][dcol] = vv[j];   // natural [k][d]
        }
        __syncthreads();

        // S = Q.K^T  (4x4 per thread): q = q0+ty*4+r, k = k0+tx*4+c
        float s[4][4] = {};
        #pragma unroll
        for (int i = 0; i < 64; i++) {
            float4 a = *(const float4*)&Qs[i][ty * 4];
            float4 b = *(const float4*)&Ks[i][tx * 4];
            float ar[4] = {a.x, a.y, a.z, a.w};
            float br[4] = {b.x, b.y, b.z, b.w};
            #pragma unroll
            for (int r = 0; r < 4; r++)
                #pragma unroll
                for (int c = 0; c < 4; c++)
                    s[r][c] += ar[r] * br[c];
        }
        // decay mask
        #pragma unroll
        for (int r = 0; r < 4; r++)
            #pragma unroll
            for (int c = 0; c < 4; c++) {
                int diff = (q0 + ty * 4 + r) - (k0 + tx * 4 + c);
                s[r][c] = (diff >= 0) ? s[r][c] * __expf((float)diff * lg) : 0.f;
            }
        __syncthreads();   // all Ks reads done before overwrite with Ss
        #pragma unroll
        for (int r = 0; r < 4; r++)
            #pragma unroll
            for (int c = 0; c < 4; c++)
                Ks[tx * 4 + c][ty * 4 + r] = s[r][c];   // Ss[k][q]
        __syncthreads();

        // O += Ss^T @ V : o[r][c] with q = ty*4+r, d = tx*4+c
        #pragma unroll
        for (int i = 0; i < 64; i++) {
            float4 a = *(const float4*)&Ks[i][ty * 4];  // Ss[k=i][q...]
            float4 b = *(const float4*)&Vs[i][tx * 4];  // V[k=i][d...]
            float ar[4] = {a.x, a.y, a.z, a.w};
            float br[4] = {b.x, b.y, b.z, b.w};
            #pragma unroll
            for (int r = 0; r < 4; r++)
                #pragma unroll
                for (int c = 0; c < 4; c++)
                    o_acc[r][c] += ar[r] * br[c];
        }
        // next iteration's first __syncthreads protects Ks/Vs reuse
    }

    // write pre-norm output into final [B,T,D] layout
    const int b = g >> 3, h = g & 7;
    #pragma unroll
    for (int r = 0; r < 4; r++) {
        int q = q0 + ty * 4 + r;
        float4 v = make_float4(o_acc[r][0], o_acc[r][1], o_acc[r][2], o_acc[r][3]);
        *(float4*)&out[((size_t)(b * T_ + q) * D_) + h * 64 + tx * 4] = v;
    }

    // group stats: per-thread partial -> wave reduce -> 1 atomic per wave
    float sm = 0.f, sq = 0.f;
    #pragma unroll
    for (int r = 0; r < 4; r++)
        #pragma unroll
        for (int c = 0; c < 4; c++) { float v = o_acc[r][c]; sm += v; sq += v * v; }
    for (int off = 32; off > 0; off >>= 1) {
        sm += __shfl_down(sm, off);
        sq += __shfl_down(sq, off);
    }
    if ((tid & 63) == 0) {
        atomicAdd(&stats[g], sm);
        atomicAdd(&stats[NG_ + g], sq);
    }
}

// ---------------- Kernel 3: GroupNorm epilogue (in place) ----------------
__global__ __launch_bounds__(256) void norm_kernel(
    float* __restrict__ out, const float* __restrict__ stats,
    const float* __restrict__ gn_w, const float* __restrict__ gn_b)
{
    int idx = blockIdx.x * 256 + threadIdx.x;
    if (idx >= B_ * T_ * D_) return;
    int c = idx & (D_ - 1);
    int b = idx >> 20;                  // T_*D_ = 2^20
    int g = b * H_ + (c >> 6);
    const float invN = 1.f / (float)(T_ * HD_);
    float mean = stats[g] * invN;
    float var  = stats[NG_ + g] * invN - mean * mean;
    float inv  = rsqrtf(var + EPS_);
    out[idx] = (out[idx] - mean) * inv * gn_w[c] + gn_b[c];
}

extern "C" void kernel_launch(void* const* d_in, const int* in_sizes, int n_in,
                              void* d_out, int out_size, void* d_ws, size_t ws_size,
                              hipStream_t stream)
{
    const float* x    = (const float*)d_in[0];
    const float* Wq   = (const float*)d_in[1];
    const float* bq   = (const float*)d_in[2];
    const float* Wk   = (const float*)d_in[3];
    const float* bk   = (const float*)d_in[4];
    const float* Wv   = (const float*)d_in[5];
    const float* bv   = (const float*)d_in[6];
    const float* gn_w = (const float*)d_in[7];
    const float* gn_b = (const float*)d_in[8];
    const float* gam  = (const float*)d_in[9];
    float* out = (float*)d_out;

    float* stats = (float*)d_ws;
    float* Qw = (float*)((char*)d_ws + 256);
    const size_t per = (size_t)B_ * H_ * T_ * HD_;   // 2M floats
    float* Kw = Qw + per;
    float* Vw = Kw + per;

    hipMemsetAsync(stats, 0, 256, stream);
    proj_kernel<<<dim3(64, 8, 3), 256, 0, stream>>>(x, Wq, Wk, Wv, bq, bk, bv, Qw, Kw, Vw);
    retention_kernel<<<dim3(32, 16), 256, 0, stream>>>(Qw, Kw, Vw, gam, out, stats);
    norm_kernel<<<8192, 256, 0, stream>>>(out, stats, gn_w, gn_b);
}

// Round 2
// 208.312 us; speedup vs baseline: 3.1223x; 3.1223x over previous
//
#include <hip/hip_runtime.h>
#include <math.h>

#define B_ 2
#define T_ 2048
#define D_ 512
#define H_ 8
#define HD_ 64
#define NG_ (B_*H_)
#define EPS_ 1e-5f

typedef __attribute__((ext_vector_type(8)))  short  short8;   // 8 bf16 (4 VGPRs)
typedef __attribute__((ext_vector_type(16))) float  floatx16; // MFMA 32x32 acc

__device__ inline floatx16 zero16() {
    floatx16 z;
#pragma unroll
    for (int i = 0; i < 16; i++) z[i] = 0.f;
    return z;
}

// round-to-nearest-even fp32 -> bf16, packed pair
__device__ inline unsigned pack2bf(float a, float b) {
    unsigned ua = __float_as_uint(a), ub = __float_as_uint(b);
    ua = (ua + 0x7fffu + ((ua >> 16) & 1u)) >> 16;
    ub = (ub + 0x7fffu + ((ub >> 16) & 1u)) >> 16;
    return ua | (ub << 16);
}

// ---------------- Kernel 1: fused QKV projection (fp32 compute, bf16 out) ----
// C[n,o] = sum_i x[n,i] * W[o,i] + b[o]
// Q,K -> [g][t][64] bf16 row-major; V -> [g][d][2048] bf16 (transposed).
__global__ __launch_bounds__(256) void proj_kernel(
    const float* __restrict__ x,
    const float* __restrict__ Wq, const float* __restrict__ Wk, const float* __restrict__ Wv,
    const float* __restrict__ bq, const float* __restrict__ bk, const float* __restrict__ bv,
    short* __restrict__ Qo, short* __restrict__ Ko, short* __restrict__ Vto)
{
    const float* W; const float* bias;
    if (blockIdx.z == 0)      { W = Wq; bias = bq; }
    else if (blockIdx.z == 1) { W = Wk; bias = bk; }
    else                      { W = Wv; bias = bv; }

    __shared__ __align__(16) float As[16][68];
    __shared__ __align__(16) float Bs[16][68];

    const int tid = threadIdx.x;
    const int n0 = blockIdx.x * 64;
    const int o0 = blockIdx.y * 64;
    const int tx = tid & 15, ty = tid >> 4;
    const int lr = tid >> 2;
    const int lc = (tid & 3) * 4;

    float acc[4][4] = {};

    for (int kk = 0; kk < D_; kk += 16) {
        float4 av  = *(const float4*)&x[(size_t)(n0 + lr) * D_ + kk + lc];
        float4 bv4 = *(const float4*)&W[(size_t)(o0 + lr) * D_ + kk + lc];
        __syncthreads();
        As[lc+0][lr] = av.x;  As[lc+1][lr] = av.y;  As[lc+2][lr] = av.z;  As[lc+3][lr] = av.w;
        Bs[lc+0][lr] = bv4.x; Bs[lc+1][lr] = bv4.y; Bs[lc+2][lr] = bv4.z; Bs[lc+3][lr] = bv4.w;
        __syncthreads();
#pragma unroll
        for (int i = 0; i < 16; i++) {
            float4 a = *(const float4*)&As[i][ty * 4];
            float4 b = *(const float4*)&Bs[i][tx * 4];
            float ar[4] = {a.x, a.y, a.z, a.w};
            float br[4] = {b.x, b.y, b.z, b.w};
#pragma unroll
            for (int r = 0; r < 4; r++)
#pragma unroll
                for (int c = 0; c < 4; c++)
                    acc[r][c] += ar[r] * br[c];
        }
    }

    const int h = o0 >> 6;
    const int b = n0 >> 11;              // whole block same batch (n0 mult of 64)
    const int g = b * H_ + h;
    const int t0 = n0 & (T_ - 1);

    if (blockIdx.z < 2) {
        short* dst = (blockIdx.z == 0) ? Qo : Ko;
#pragma unroll
        for (int r = 0; r < 4; r++) {
            int t = t0 + ty * 4 + r;
            float b0 = bias[o0 + tx*4 + 0], b1 = bias[o0 + tx*4 + 1];
            float b2 = bias[o0 + tx*4 + 2], b3 = bias[o0 + tx*4 + 3];
            uint2 v;
            v.x = pack2bf(acc[r][0] + b0, acc[r][1] + b1);
            v.y = pack2bf(acc[r][2] + b2, acc[r][3] + b3);
            *(uint2*)&dst[((size_t)g * T_ + t) * HD_ + tx * 4] = v;
        }
    } else {
        // V transposed: Vt[g][d][t]
#pragma unroll
        for (int c = 0; c < 4; c++) {
            int d = tx * 4 + c;
            float bc = bias[o0 + d];
            uint2 v;
            v.x = pack2bf(acc[0][c] + bc, acc[1][c] + bc);
            v.y = pack2bf(acc[2][c] + bc, acc[3][c] + bc);
            *(uint2*)&Vto[((size_t)g * HD_ + d) * T_ + t0 + ty * 4] = v;
        }
    }
}

// ---------------- Kernel 2: windowed retention, MFMA bf16 ----------------
// grid (32 qtiles, 16 groups), 256 thr = 4 waves: wave = (qh = w&1, ks = w>>1).
// Wave computes O[32q x 64d] partial over ktiles of its parity; cross-parity
// reduce via LDS at the end. S^T = K·Q^T (MFMA), decay factorized (no expf in
// loop), S^T -> A-operand via xor-32 shuffle in registers, O += S·V (MFMA).
__global__ __launch_bounds__(256) void retention_kernel(
    const short* __restrict__ Q, const short* __restrict__ K, const short* __restrict__ Vt,
    const float* __restrict__ gamma_p,
    float* __restrict__ out,     // [B,T,D] pre-norm fp32
    float* __restrict__ stats)   // [16 sums][16 sumsq]
{
    __shared__ float red[2][32 * 64];   // per qh: 32q x 64d partial, 16 KB

    const int tid  = threadIdx.x;
    const int w    = tid >> 6, lane = tid & 63;
    const int qh   = w & 1,  ks  = w >> 1;
    const int hi   = lane >> 5, ln = lane & 31;
    const int qt   = blockIdx.x, g = blockIdx.y;
    const int q0   = qt * 64;

    const float gamma = gamma_p[0];
    const float lg = logf(gamma);
    int kt0 = 0;
    if (lg < -1e-6f) {
        int maxd = (int)(-34.0f / lg) + 64;   // gamma^maxd < ~2e-15
        kt0 = qt - (maxd >> 6);
        if (kt0 < 0) kt0 = 0;
    }

    // Q fragments (B-operand of S^T = K*Q^T): col q = ln, k-dim = hd
    const short* Qbase = Q + ((size_t)g * T_ + q0 + qh * 32 + ln) * HD_;
    short8 qf[4];
#pragma unroll
    for (int c = 0; c < 4; c++) qf[c] = *(const short8*)(Qbase + 16 * c + 8 * hi);

    // decay factorization: gamma^(q-k) = Alane * Ckt * G32^kh * Er[r]
    // q-k = (qh*32+ln-4*hi) + (q0-k0) - kh*32 - ((r&3)+8*(r>>2))
    const float Alane = __expf(lg * (float)(qh * 32 + ln - 4 * hi));
    const float G32   = __expf(-lg * 32.0f);
    float Er[16];
#pragma unroll
    for (int r = 0; r < 16; r++) Er[r] = __expf(-lg * (float)((r & 3) + 8 * (r >> 2)));

    floatx16 oacc[2] = {zero16(), zero16()};

    for (int kt = kt0 + ((ks - kt0) & 1); kt <= qt; kt += 2) {
        const int k0 = kt * 64;
        const short* Kbase = K + ((size_t)g * T_ + k0) * HD_;

        // S^T quadrants (kh = k-half): A = K rows, B = Q cols
        floatx16 st[2];
#pragma unroll
        for (int kh = 0; kh < 2; kh++) {
            const short* kp = Kbase + (size_t)(kh * 32 + ln) * HD_ + 8 * hi;
            floatx16 acc = zero16();
#pragma unroll
            for (int c = 0; c < 4; c++) {
                short8 a = *(const short8*)(kp + 16 * c);
                acc = __builtin_amdgcn_mfma_f32_32x32x16_bf16(a, qf[c], acc, 0, 0, 0);
            }
            st[kh] = acc;
        }

        // decay + causal mask (diag tile only)
        const float Ckt = __expf(lg * (float)(q0 - k0));
        const float base0 = Alane * Ckt;
        const bool diag = (kt == qt);
#pragma unroll
        for (int kh = 0; kh < 2; kh++) {
            float bb = base0 * (kh ? G32 : 1.0f);
#pragma unroll
            for (int r = 0; r < 16; r++) {
                float v = st[kh][r] * (bb * Er[r]);
                if (diag) {
                    int kloc = kh * 32 + (r & 3) + 8 * (r >> 2) + 4 * hi;
                    int qloc = qh * 32 + ln;
                    if (qloc < kloc) v = 0.f;
                }
                st[kh][r] = v;
            }
        }

        // PV: O[q][d] += S[q][k] * V[k][d], 4 k-chunks of 16
#pragma unroll
        for (int c = 0; c < 4; c++) {
            const int kh = c >> 1, rb = 8 * (c & 1);
            unsigned p0 = pack2bf(st[kh][rb+0], st[kh][rb+1]);
            unsigned p1 = pack2bf(st[kh][rb+2], st[kh][rb+3]);
            unsigned p2 = pack2bf(st[kh][rb+4], st[kh][rb+5]);
            unsigned p3 = pack2bf(st[kh][rb+6], st[kh][rb+7]);
            unsigned t0s = (unsigned)__shfl_xor((int)(hi ? p0 : p2), 32, 64);
            unsigned t1s = (unsigned)__shfl_xor((int)(hi ? p1 : p3), 32, 64);
            uint4 aw;
            aw.x = hi ? t0s : p0;  aw.y = hi ? t1s : p1;
            aw.z = hi ? p2  : t0s; aw.w = hi ? p3  : t1s;
            short8 afr = *reinterpret_cast<short8*>(&aw);
#pragma unroll
            for (int dh = 0; dh < 2; dh++) {
                const short* vp = Vt + ((size_t)g * HD_ + dh * 32 + ln) * T_ + k0 + 16 * c + 8 * hi;
                short8 bfr = *(const short8*)vp;
                oacc[dh] = __builtin_amdgcn_mfma_f32_32x32x16_bf16(afr, bfr, oacc[dh], 0, 0, 0);
            }
        }
    }

    // cross-parity reduction + write + stats
    float* rp = &red[qh][0];
    if (ks == 1) {
#pragma unroll
        for (int dh = 0; dh < 2; dh++)
#pragma unroll
            for (int r = 0; r < 16; r++) {
                int qloc = (r & 3) + 8 * (r >> 2) + 4 * hi;
                rp[qloc * 64 + dh * 32 + ln] = oacc[dh][r];
            }
    }
    __syncthreads();
    if (ks == 0) {
        const int b = g >> 3, h = g & 7;
        float sm = 0.f, sq = 0.f;
#pragma unroll
        for (int dh = 0; dh < 2; dh++)
#pragma unroll
            for (int r = 0; r < 16; r++) {
                int qloc = (r & 3) + 8 * (r >> 2) + 4 * hi;
                float v = oacc[dh][r] + rp[qloc * 64 + dh * 32 + ln];
                int q = q0 + qh * 32 + qloc;
                out[((size_t)(b * T_ + q)) * D_ + h * 64 + dh * 32 + ln] = v;
                sm += v; sq += v * v;
            }
        for (int off = 32; off > 0; off >>= 1) {
            sm += __shfl_down(sm, off);
            sq += __shfl_down(sq, off);
        }
        if (lane == 0) {
            atomicAdd(&stats[g], sm);
            atomicAdd(&stats[NG_ + g], sq);
        }
    }
}

// ---------------- Kernel 3: GroupNorm epilogue (in place) ----------------
__global__ __launch_bounds__(256) void norm_kernel(
    float* __restrict__ out, const float* __restrict__ stats,
    const float* __restrict__ gn_w, const float* __restrict__ gn_b)
{
    int idx = blockIdx.x * 256 + threadIdx.x;
    if (idx >= B_ * T_ * D_) return;
    int c = idx & (D_ - 1);
    int b = idx >> 20;
    int g = b * H_ + (c >> 6);
    const float invN = 1.f / (float)(T_ * HD_);
    float mean = stats[g] * invN;
    float var  = stats[NG_ + g] * invN - mean * mean;
    float inv  = rsqrtf(var + EPS_);
    out[idx] = (out[idx] - mean) * inv * gn_w[c] + gn_b[c];
}

extern "C" void kernel_launch(void* const* d_in, const int* in_sizes, int n_in,
                              void* d_out, int out_size, void* d_ws, size_t ws_size,
                              hipStream_t stream)
{
    const float* x    = (const float*)d_in[0];
    const float* Wq   = (const float*)d_in[1];
    const float* bq   = (const float*)d_in[2];
    const float* Wk   = (const float*)d_in[3];
    const float* bk   = (const float*)d_in[4];
    const float* Wv   = (const float*)d_in[5];
    const float* bv   = (const float*)d_in[6];
    const float* gn_w = (const float*)d_in[7];
    const float* gn_b = (const float*)d_in[8];
    const float* gam  = (const float*)d_in[9];
    float* out = (float*)d_out;

    float* stats = (float*)d_ws;
    short* Qw = (short*)((char*)d_ws + 256);
    const size_t per = (size_t)B_ * H_ * T_ * HD_;   // 2M elements
    short* Kw  = Qw + per;
    short* Vtw = Kw + per;

    hipMemsetAsync(stats, 0, 256, stream);
    proj_kernel<<<dim3(64, 8, 3), 256, 0, stream>>>(x, Wq, Wk, Wv, bq, bk, bv, Qw, Kw, Vtw);
    retention_kernel<<<dim3(32, 16), 256, 0, stream>>>(Qw, Kw, Vtw, gam, out, stats);
    norm_kernel<<<8192, 256, 0, stream>>>(out, stats, gn_w, gn_b);
}

// Round 3
// 140.678 us; speedup vs baseline: 4.6234x; 1.4808x over previous
//
#include <hip/hip_runtime.h>
#include <math.h>

#define B_ 2
#define T_ 2048
#define D_ 512
#define H_ 8
#define HD_ 64
#define NG_ (B_*H_)
#define EPS_ 1e-5f

typedef __attribute__((ext_vector_type(8)))  short  short8;   // 8 bf16 (4 VGPRs)
typedef __attribute__((ext_vector_type(16))) float  floatx16; // MFMA 32x32 acc

__device__ inline floatx16 zero16() {
    floatx16 z;
#pragma unroll
    for (int i = 0; i < 16; i++) z[i] = 0.f;
    return z;
}

// round-to-nearest-even fp32 -> bf16
__device__ inline unsigned pack2bf(float a, float b) {
    unsigned ua = __float_as_uint(a), ub = __float_as_uint(b);
    ua = (ua + 0x7fffu + ((ua >> 16) & 1u)) >> 16;
    ub = (ub + 0x7fffu + ((ub >> 16) & 1u)) >> 16;
    return ua | (ub << 16);
}
__device__ inline short bf1(float a) {
    unsigned ua = __float_as_uint(a);
    return (short)((ua + 0x7fffu + ((ua >> 16) & 1u)) >> 16);
}

// ---------------- Kernel 0: fp32 -> bf16 convert (x and Wq|Wk|Wv) ----------
// xb: [4096][512]; Wb: [3][512][512]
__global__ __launch_bounds__(256) void convert_kernel(
    const float* __restrict__ x,
    const float* __restrict__ Wq, const float* __restrict__ Wk, const float* __restrict__ Wv,
    short* __restrict__ xb, short* __restrict__ Wb)
{
    const int XN = 4096 * 512;       // 2M
    const int WN = 512 * 512;        // 256K
    size_t e = ((size_t)blockIdx.x * 256 + threadIdx.x) * 8;
    const float* src; short* dst;
    if (e < XN)               { src = x  + e;               dst = xb + e; }
    else if (e < XN + WN)     { src = Wq + (e - XN);        dst = Wb + (e - XN); }
    else if (e < XN + 2*WN)   { src = Wk + (e - XN - WN);   dst = Wb + (e - XN); }
    else                      { src = Wv + (e - XN - 2*WN); dst = Wb + (e - XN); }
    float4 a = *(const float4*)src;
    float4 b = *(const float4*)(src + 4);
    uint4 o;
    o.x = pack2bf(a.x, a.y); o.y = pack2bf(a.z, a.w);
    o.z = pack2bf(b.x, b.y); o.w = pack2bf(b.z, b.w);
    *(uint4*)dst = o;
}

// ---------------- Kernel 1: QKV projection via MFMA bf16 ----------------
// C = x @ W^T + b. 128x128 tile/block, 4 waves each 64x64 (2x2 32x32 MFMA).
// Q,K -> [g][t][64] (lane axis = channel); V -> Vt[g][d][2048] (lane = token).
__global__ __launch_bounds__(256) void proj_mfma(
    const short* __restrict__ xb, const short* __restrict__ Wb,
    const float* __restrict__ bq, const float* __restrict__ bk, const float* __restrict__ bv,
    short* __restrict__ Qo, short* __restrict__ Ko, short* __restrict__ Vto)
{
    __shared__ short Xs[128 * 64];   // [token][k] 16 KB
    __shared__ short Ws2[128 * 64];  // [chan][k]  16 KB

    const int tid = threadIdx.x;
    const int w = tid >> 6, lane = tid & 63;
    const int hi = lane >> 5, ln = lane & 31;
    const int mt0 = blockIdx.x * 128;
    const int nt0 = blockIdx.y * 128;
    const int z = blockIdx.z;
    const bool isV = (z == 2);
    const float* bias = (z == 0) ? bq : (z == 1) ? bk : bv;
    const short* Wz = Wb + (size_t)z * 512 * 512;

    const int srow = w * 32 + (lane >> 3);   // staging row within tile
    const int scol = (lane & 7) * 8;         // staging col (shorts)
    const int mh = w & 1, nh = w >> 1;

    floatx16 acc[2][2] = {{zero16(), zero16()}, {zero16(), zero16()}};

    for (int k0 = 0; k0 < 512; k0 += 64) {
        __syncthreads();   // previous iteration's fragment reads done
#pragma unroll
        for (int c = 0; c < 4; c++) {
            const short* gx = xb + (size_t)(mt0 + srow + c * 8) * 512 + k0 + scol;
            const short* gw = Wz + (size_t)(nt0 + srow + c * 8) * 512 + k0 + scol;
            short* lx = Xs  + (w * 32 + c * 8) * 64;
            short* lw = Ws2 + (w * 32 + c * 8) * 64;
            __builtin_amdgcn_global_load_lds(
                (const __attribute__((address_space(1))) unsigned*)gx,
                (__attribute__((address_space(3))) unsigned*)lx, 16, 0, 0);
            __builtin_amdgcn_global_load_lds(
                (const __attribute__((address_space(1))) unsigned*)gw,
                (__attribute__((address_space(3))) unsigned*)lw, 16, 0, 0);
        }
        __syncthreads();   // staging complete (vmcnt drained by barrier)

#pragma unroll
        for (int kk = 0; kk < 4; kk++) {
            short8 xf[2], wf[2];
#pragma unroll
            for (int s = 0; s < 2; s++) {
                xf[s] = *(const short8*)(Xs  + (mh * 64 + s * 32 + ln) * 64 + kk * 16 + hi * 8);
                wf[s] = *(const short8*)(Ws2 + (nh * 64 + s * 32 + ln) * 64 + kk * 16 + hi * 8);
            }
#pragma unroll
            for (int a = 0; a < 2; a++)
#pragma unroll
                for (int b = 0; b < 2; b++)
                    acc[a][b] = isV
                        ? __builtin_amdgcn_mfma_f32_32x32x16_bf16(wf[a], xf[b], acc[a][b], 0, 0, 0)
                        : __builtin_amdgcn_mfma_f32_32x32x16_bf16(xf[a], wf[b], acc[a][b], 0, 0, 0);
        }
    }

    const int head = blockIdx.y * 2 + nh;

    if (!isV) {
        // D[m][n]: rows (regs) = tokens, cols (lane) = channels
        short* dst = (z == 0) ? Qo : Ko;
        float bias_v[2];
#pragma unroll
        for (int b = 0; b < 2; b++) bias_v[b] = bias[nt0 + nh * 64 + b * 32 + ln];
#pragma unroll
        for (int a = 0; a < 2; a++) {
            const int mbase = mt0 + mh * 64 + a * 32;
#pragma unroll
            for (int r = 0; r < 16; r++) {
                int m = mbase + (r & 3) + 8 * (r >> 2) + 4 * hi;
                int batch = m >> 11, t = m & (T_ - 1);
                size_t rowb = ((size_t)(batch * H_ + head) * T_ + t) * HD_;
#pragma unroll
                for (int b = 0; b < 2; b++)
                    dst[rowb + b * 32 + ln] = bf1(acc[a][b][r] + bias_v[b]);
            }
        }
    } else {
        // D[n][m]: rows (regs) = channels, cols (lane) = tokens
#pragma unroll
        for (int a = 0; a < 2; a++) {
#pragma unroll
            for (int r = 0; r < 16; r++) {
                int chan = nt0 + nh * 64 + a * 32 + (r & 3) + 8 * (r >> 2) + 4 * hi;
                int d = chan & (HD_ - 1);
                float bv_ = bias[chan];
#pragma unroll
                for (int b = 0; b < 2; b++) {
                    int m = mt0 + mh * 64 + b * 32 + ln;
                    int batch = m >> 11, t = m & (T_ - 1);
                    Vto[((size_t)(batch * H_ + head) * HD_ + d) * T_ + t] = bf1(acc[a][b][r] + bv_);
                }
            }
        }
    }
}

// ---------------- Kernel 2: windowed retention, MFMA bf16 ----------------
__global__ __launch_bounds__(256) void retention_kernel(
    const short* __restrict__ Q, const short* __restrict__ K, const short* __restrict__ Vt,
    const float* __restrict__ gamma_p,
    float* __restrict__ out,     // [B,T,D] pre-norm fp32
    float* __restrict__ stats)   // [16 sums][16 sumsq]
{
    __shared__ float red[2][32 * 64];   // per qh: 32q x 64d partial, 16 KB

    const int tid  = threadIdx.x;
    const int w    = tid >> 6, lane = tid & 63;
    const int qh   = w & 1,  ks  = w >> 1;
    const int hi   = lane >> 5, ln = lane & 31;
    const int qt   = blockIdx.x, g = blockIdx.y;
    const int q0   = qt * 64;

    const float gamma = gamma_p[0];
    const float lg = logf(gamma);
    int kt0 = 0;
    if (lg < -1e-6f) {
        int maxd = (int)(-34.0f / lg) + 64;   // gamma^maxd < ~2e-15
        kt0 = qt - (maxd >> 6);
        if (kt0 < 0) kt0 = 0;
    }

    const short* Qbase = Q + ((size_t)g * T_ + q0 + qh * 32 + ln) * HD_;
    short8 qf[4];
#pragma unroll
    for (int c = 0; c < 4; c++) qf[c] = *(const short8*)(Qbase + 16 * c + 8 * hi);

    const float Alane = __expf(lg * (float)(qh * 32 + ln - 4 * hi));
    const float G32   = __expf(-lg * 32.0f);
    float Er[16];
#pragma unroll
    for (int r = 0; r < 16; r++) Er[r] = __expf(-lg * (float)((r & 3) + 8 * (r >> 2)));

    floatx16 oacc[2] = {zero16(), zero16()};

    for (int kt = kt0 + ((ks - kt0) & 1); kt <= qt; kt += 2) {
        const int k0 = kt * 64;
        const short* Kbase = K + ((size_t)g * T_ + k0) * HD_;

        floatx16 st[2];
#pragma unroll
        for (int kh = 0; kh < 2; kh++) {
            const short* kp = Kbase + (size_t)(kh * 32 + ln) * HD_ + 8 * hi;
            floatx16 acc = zero16();
#pragma unroll
            for (int c = 0; c < 4; c++) {
                short8 a = *(const short8*)(kp + 16 * c);
                acc = __builtin_amdgcn_mfma_f32_32x32x16_bf16(a, qf[c], acc, 0, 0, 0);
            }
            st[kh] = acc;
        }

        const float Ckt = __expf(lg * (float)(q0 - k0));
        const float base0 = Alane * Ckt;
        const bool diag = (kt == qt);
#pragma unroll
        for (int kh = 0; kh < 2; kh++) {
            float bb = base0 * (kh ? G32 : 1.0f);
#pragma unroll
            for (int r = 0; r < 16; r++) {
                float v = st[kh][r] * (bb * Er[r]);
                if (diag) {
                    int kloc = kh * 32 + (r & 3) + 8 * (r >> 2) + 4 * hi;
                    int qloc = qh * 32 + ln;
                    if (qloc < kloc) v = 0.f;
                }
                st[kh][r] = v;
            }
        }

#pragma unroll
        for (int c = 0; c < 4; c++) {
            const int kh = c >> 1, rb = 8 * (c & 1);
            unsigned p0 = pack2bf(st[kh][rb+0], st[kh][rb+1]);
            unsigned p1 = pack2bf(st[kh][rb+2], st[kh][rb+3]);
            unsigned p2 = pack2bf(st[kh][rb+4], st[kh][rb+5]);
            unsigned p3 = pack2bf(st[kh][rb+6], st[kh][rb+7]);
            unsigned t0s = (unsigned)__shfl_xor((int)(hi ? p0 : p2), 32, 64);
            unsigned t1s = (unsigned)__shfl_xor((int)(hi ? p1 : p3), 32, 64);
            uint4 aw;
            aw.x = hi ? t0s : p0;  aw.y = hi ? t1s : p1;
            aw.z = hi ? p2  : t0s; aw.w = hi ? p3  : t1s;
            short8 afr = *reinterpret_cast<short8*>(&aw);
#pragma unroll
            for (int dh = 0; dh < 2; dh++) {
                const short* vp = Vt + ((size_t)g * HD_ + dh * 32 + ln) * T_ + k0 + 16 * c + 8 * hi;
                short8 bfr = *(const short8*)vp;
                oacc[dh] = __builtin_amdgcn_mfma_f32_32x32x16_bf16(afr, bfr, oacc[dh], 0, 0, 0);
            }
        }
    }

    float* rp = &red[qh][0];
    if (ks == 1) {
#pragma unroll
        for (int dh = 0; dh < 2; dh++)
#pragma unroll
            for (int r = 0; r < 16; r++) {
                int qloc = (r & 3) + 8 * (r >> 2) + 4 * hi;
                rp[qloc * 64 + dh * 32 + ln] = oacc[dh][r];
            }
    }
    __syncthreads();
    if (ks == 0) {
        const int b = g >> 3, h = g & 7;
        float sm = 0.f, sq = 0.f;
#pragma unroll
        for (int dh = 0; dh < 2; dh++)
#pragma unroll
            for (int r = 0; r < 16; r++) {
                int qloc = (r & 3) + 8 * (r >> 2) + 4 * hi;
                float v = oacc[dh][r] + rp[qloc * 64 + dh * 32 + ln];
                int q = q0 + qh * 32 + qloc;
                out[((size_t)(b * T_ + q)) * D_ + h * 64 + dh * 32 + ln] = v;
                sm += v; sq += v * v;
            }
        for (int off = 32; off > 0; off >>= 1) {
            sm += __shfl_down(sm, off);
            sq += __shfl_down(sq, off);
        }
        if (lane == 0) {
            atomicAdd(&stats[g], sm);
            atomicAdd(&stats[NG_ + g], sq);
        }
    }
}

// ---------------- Kernel 3: GroupNorm epilogue (in place) ----------------
__global__ __launch_bounds__(256) void norm_kernel(
    float* __restrict__ out, const float* __restrict__ stats,
    const float* __restrict__ gn_w, const float* __restrict__ gn_b)
{
    int idx = blockIdx.x * 256 + threadIdx.x;
    if (idx >= B_ * T_ * D_) return;
    int c = idx & (D_ - 1);
    int b = idx >> 20;
    int g = b * H_ + (c >> 6);
    const float invN = 1.f / (float)(T_ * HD_);
    float mean = stats[g] * invN;
    float var  = stats[NG_ + g] * invN - mean * mean;
    float inv  = rsqrtf(var + EPS_);
    out[idx] = (out[idx] - mean) * inv * gn_w[c] + gn_b[c];
}

extern "C" void kernel_launch(void* const* d_in, const int* in_sizes, int n_in,
                              void* d_out, int out_size, void* d_ws, size_t ws_size,
                              hipStream_t stream)
{
    const float* x    = (const float*)d_in[0];
    const float* Wq   = (const float*)d_in[1];
    const float* bq   = (const float*)d_in[2];
    const float* Wk   = (const float*)d_in[3];
    const float* bk   = (const float*)d_in[4];
    const float* Wv   = (const float*)d_in[5];
    const float* bv   = (const float*)d_in[6];
    const float* gn_w = (const float*)d_in[7];
    const float* gn_b = (const float*)d_in[8];
    const float* gam  = (const float*)d_in[9];
    float* out = (float*)d_out;

    const size_t per = (size_t)B_ * H_ * T_ * HD_;   // 2M elements
    float* stats = (float*)d_ws;
    short* Qw  = (short*)((char*)d_ws + 256);
    short* Kw  = Qw + per;
    short* Vtw = Kw + per;
    short* xb  = Vtw + per;
    short* Wb  = xb + per;                            // 3*512*512 shorts

    hipMemsetAsync(stats, 0, 256, stream);
    convert_kernel<<<1408, 256, 0, stream>>>(x, Wq, Wk, Wv, xb, Wb);
    proj_mfma<<<dim3(32, 4, 3), 256, 0, stream>>>(xb, Wb, bq, bk, bv, Qw, Kw, Vtw);
    retention_kernel<<<dim3(32, 16), 256, 0, stream>>>(Qw, Kw, Vtw, gam, out, stats);
    norm_kernel<<<8192, 256, 0, stream>>>(out, stats, gn_w, gn_b);
}

// Round 4
// 139.204 us; speedup vs baseline: 4.6723x; 1.0106x over previous
//
#include <hip/hip_runtime.h>
#include <math.h>

#define B_ 2
#define T_ 2048
#define D_ 512
#define H_ 8
#define HD_ 64
#define NG_ (B_*H_)
#define EPS_ 1e-5f

typedef __attribute__((ext_vector_type(8)))  short  short8;   // 8 bf16 (4 VGPRs)
typedef __attribute__((ext_vector_type(16))) float  floatx16; // MFMA 32x32 acc

__device__ inline floatx16 zero16() {
    floatx16 z;
#pragma unroll
    for (int i = 0; i < 16; i++) z[i] = 0.f;
    return z;
}

// round-to-nearest-even fp32 -> bf16
__device__ inline unsigned pack2bf(float a, float b) {
    unsigned ua = __float_as_uint(a), ub = __float_as_uint(b);
    ua = (ua + 0x7fffu + ((ua >> 16) & 1u)) >> 16;
    ub = (ub + 0x7fffu + ((ub >> 16) & 1u)) >> 16;
    return ua | (ub << 16);
}
__device__ inline short bf1(float a) {
    unsigned ua = __float_as_uint(a);
    return (short)((ua + 0x7fffu + ((ua >> 16) & 1u)) >> 16);
}

// ---------------- Kernel 0: fp32 -> bf16 convert (x and Wq|Wk|Wv) ----------
__global__ __launch_bounds__(256) void convert_kernel(
    const float* __restrict__ x,
    const float* __restrict__ Wq, const float* __restrict__ Wk, const float* __restrict__ Wv,
    short* __restrict__ xb, short* __restrict__ Wb)
{
    const int XN = 4096 * 512;       // 2M
    const int WN = 512 * 512;        // 256K
    size_t e = ((size_t)blockIdx.x * 256 + threadIdx.x) * 8;
    const float* src; short* dst;
    if (e < XN)               { src = x  + e;               dst = xb + e; }
    else if (e < XN + WN)     { src = Wq + (e - XN);        dst = Wb + (e - XN); }
    else if (e < XN + 2*WN)   { src = Wk + (e - XN - WN);   dst = Wb + (e - XN); }
    else                      { src = Wv + (e - XN - 2*WN); dst = Wb + (e - XN); }
    float4 a = *(const float4*)src;
    float4 b = *(const float4*)(src + 4);
    uint4 o;
    o.x = pack2bf(a.x, a.y); o.y = pack2bf(a.z, a.w);
    o.z = pack2bf(b.x, b.y); o.w = pack2bf(b.z, b.w);
    *(uint4*)dst = o;
}

// ---------------- Kernel 1: QKV projection via MFMA bf16 ----------------
// C = x @ W^T + b. 64x128 tile/block (3 blocks/CU), 4 waves each 32m x 64n.
// Q,K -> [g][t][64] (lane = channel); V -> Vt[g][d][2048] (lane = token).
__global__ __launch_bounds__(256) void proj_mfma(
    const short* __restrict__ xb, const short* __restrict__ Wb,
    const float* __restrict__ bq, const float* __restrict__ bk, const float* __restrict__ bv,
    short* __restrict__ Qo, short* __restrict__ Ko, short* __restrict__ Vto)
{
    __shared__ short Xs[64 * 64];    // [token][k]  8 KB
    __shared__ short Ws2[128 * 64];  // [chan][k]  16 KB

    const int tid = threadIdx.x;
    const int w = tid >> 6, lane = tid & 63;
    const int hi = lane >> 5, ln = lane & 31;
    const int mt0 = blockIdx.x * 64;
    const int nt0 = blockIdx.y * 128;
    const int z = blockIdx.z;
    const bool isV = (z == 2);
    const float* bias = (z == 0) ? bq : (z == 1) ? bk : bv;
    const short* Wz = Wb + (size_t)z * 512 * 512;

    const int srow = tid >> 3;       // 0..31
    const int scol = (tid & 7) * 8;  // shorts
    const int mh = w & 1, nh = w >> 1;

    floatx16 acc[2] = {zero16(), zero16()};

    for (int k0 = 0; k0 < 512; k0 += 64) {
        __syncthreads();
#pragma unroll
        for (int i = 0; i < 2; i++) {
            const short* gx = xb + (size_t)(mt0 + srow + i * 32) * 512 + k0 + scol;
            short* lx = Xs + (srow + i * 32) * 64 + scol;
            __builtin_amdgcn_global_load_lds(
                (const __attribute__((address_space(1))) unsigned*)gx,
                (__attribute__((address_space(3))) unsigned*)lx, 16, 0, 0);
        }
#pragma unroll
        for (int i = 0; i < 4; i++) {
            const short* gw = Wz + (size_t)(nt0 + srow + i * 32) * 512 + k0 + scol;
            short* lw = Ws2 + (srow + i * 32) * 64 + scol;
            __builtin_amdgcn_global_load_lds(
                (const __attribute__((address_space(1))) unsigned*)gw,
                (__attribute__((address_space(3))) unsigned*)lw, 16, 0, 0);
        }
        __syncthreads();

#pragma unroll
        for (int kk = 0; kk < 4; kk++) {
            short8 xf = *(const short8*)(Xs + (mh * 32 + ln) * 64 + kk * 16 + hi * 8);
            short8 wf[2];
#pragma unroll
            for (int s = 0; s < 2; s++)
                wf[s] = *(const short8*)(Ws2 + (nh * 64 + s * 32 + ln) * 64 + kk * 16 + hi * 8);
#pragma unroll
            for (int b = 0; b < 2; b++)
                acc[b] = isV
                    ? __builtin_amdgcn_mfma_f32_32x32x16_bf16(wf[b], xf, acc[b], 0, 0, 0)
                    : __builtin_amdgcn_mfma_f32_32x32x16_bf16(xf, wf[b], acc[b], 0, 0, 0);
        }
    }

    const int head = blockIdx.y * 2 + nh;

    if (!isV) {
        short* dst = (z == 0) ? Qo : Ko;
        float bias_v[2];
#pragma unroll
        for (int b = 0; b < 2; b++) bias_v[b] = bias[nt0 + nh * 64 + b * 32 + ln];
#pragma unroll
        for (int r = 0; r < 16; r++) {
            int m = mt0 + mh * 32 + (r & 3) + 8 * (r >> 2) + 4 * hi;
            int batch = m >> 11, t = m & (T_ - 1);
            size_t rowb = ((size_t)(batch * H_ + head) * T_ + t) * HD_;
#pragma unroll
            for (int b = 0; b < 2; b++)
                dst[rowb + b * 32 + ln] = bf1(acc[b][r] + bias_v[b]);
        }
    } else {
        const int m = mt0 + mh * 32 + ln;
        const int batch = m >> 11, t = m & (T_ - 1);
#pragma unroll
        for (int b = 0; b < 2; b++) {
#pragma unroll
            for (int r = 0; r < 16; r++) {
                int chan = nt0 + nh * 64 + b * 32 + (r & 3) + 8 * (r >> 2) + 4 * hi;
                int d = chan & (HD_ - 1);
                Vto[((size_t)(batch * H_ + head) * HD_ + d) * T_ + t] = bf1(acc[b][r] + bias[chan]);
            }
        }
    }
}

// ---------------- Kernel 2: windowed retention, MFMA bf16, 4-way k split ---
// grid (64 q-tiles of 32, 16 groups), 256 thr = 4 waves = k-parity 0..3.
// Wave computes O[32q x 64d] over its ktiles; 4-way reduce via LDS.
__global__ __launch_bounds__(256, 3) void retention_kernel(
    const short* __restrict__ Q, const short* __restrict__ K, const short* __restrict__ Vt,
    const float* __restrict__ gamma_p,
    float* __restrict__ out,     // [B,T,D] pre-norm fp32
    float* __restrict__ stats)   // [16 sums][16 sumsq]
{
    __shared__ float red[3][32 * 64];   // partials from waves 1..3, 24 KB

    const int tid  = threadIdx.x;
    const int ks   = tid >> 6, lane = tid & 63;
    const int hi   = lane >> 5, ln = lane & 31;
    const int qtt  = blockIdx.x, g = blockIdx.y;
    const int q0   = qtt * 32;          // global query base
    const int qt   = qtt >> 1;          // 64-wide ktile index containing q0

    const float gamma = gamma_p[0];
    const float lg = logf(gamma);
    int kt0 = 0;
    if (lg < -1e-6f) {
        int maxd = (int)(-34.0f / lg) + 64;   // gamma^maxd < ~2e-15
        kt0 = qt - (maxd >> 6);
        if (kt0 < 0) kt0 = 0;
    }

    // Q fragments (B-operand of S^T = K*Q^T): col q = ln
    const short* Qbase = Q + ((size_t)g * T_ + q0 + ln) * HD_;
    short8 qf[4];
#pragma unroll
    for (int c = 0; c < 4; c++) qf[c] = *(const short8*)(Qbase + 16 * c + 8 * hi);

    // decay: gamma^(q-k) = Alane * Ckt * G32^kh * Ea[r&3]*Eb[r>>2]
    const float Alane = __expf(lg * (float)(ln - 4 * hi));
    const float G32   = __expf(-lg * 32.0f);
    float Ea[4], Eb[4];
#pragma unroll
    for (int j = 0; j < 4; j++) { Ea[j] = __expf(-lg * (float)j); Eb[j] = __expf(-lg * (float)(8 * j)); }
    const int qrel = (qtt & 1) * 32 + ln;   // q within its 64-ktile

    floatx16 oacc[2] = {zero16(), zero16()};

    for (int kt = kt0 + ((ks - kt0) & 3); kt <= qt; kt += 4) {
        const int k0 = kt * 64;
        const short* Kbase = K + ((size_t)g * T_ + k0) * HD_;

        // S^T quadrants: A = K rows, B = Q cols
        floatx16 st[2];
#pragma unroll
        for (int kh = 0; kh < 2; kh++) {
            const short* kp = Kbase + (size_t)(kh * 32 + ln) * HD_ + 8 * hi;
            floatx16 acc = zero16();
#pragma unroll
            for (int c = 0; c < 4; c++) {
                short8 a = *(const short8*)(kp + 16 * c);
                acc = __builtin_amdgcn_mfma_f32_32x32x16_bf16(a, qf[c], acc, 0, 0, 0);
            }
            st[kh] = acc;
        }

        // V fragments in flight during decay+pack
        short8 vf[4][2];
#pragma unroll
        for (int c = 0; c < 4; c++)
#pragma unroll
            for (int dh = 0; dh < 2; dh++)
                vf[c][dh] = *(const short8*)(Vt + ((size_t)g * HD_ + dh * 32 + ln) * T_ + k0 + 16 * c + 8 * hi);

        const float Ckt = __expf(lg * (float)(q0 - k0));
        const float base0 = Alane * Ckt;
        const bool diag = (kt == qt);
#pragma unroll
        for (int kh = 0; kh < 2; kh++) {
            float bb = base0 * (kh ? G32 : 1.0f);
#pragma unroll
            for (int r = 0; r < 16; r++) {
                float v = st[kh][r] * (bb * Ea[r & 3] * Eb[r >> 2]);
                if (diag) {
                    int kloc = kh * 32 + (r & 3) + 8 * (r >> 2) + 4 * hi;
                    if (qrel < kloc) v = 0.f;
                }
                st[kh][r] = v;
            }
        }

        // PV: O[q][d] += S[q][k] * V[k][d]
#pragma unroll
        for (int c = 0; c < 4; c++) {
            const int kh = c >> 1, rb = 8 * (c & 1);
            unsigned p0 = pack2bf(st[kh][rb+0], st[kh][rb+1]);
            unsigned p1 = pack2bf(st[kh][rb+2], st[kh][rb+3]);
            unsigned p2 = pack2bf(st[kh][rb+4], st[kh][rb+5]);
            unsigned p3 = pack2bf(st[kh][rb+6], st[kh][rb+7]);
            unsigned t0s = (unsigned)__shfl_xor((int)(hi ? p0 : p2), 32, 64);
            unsigned t1s = (unsigned)__shfl_xor((int)(hi ? p1 : p3), 32, 64);
            uint4 aw;
            aw.x = hi ? t0s : p0;  aw.y = hi ? t1s : p1;
            aw.z = hi ? p2  : t0s; aw.w = hi ? p3  : t1s;
            short8 afr = *reinterpret_cast<short8*>(&aw);
#pragma unroll
            for (int dh = 0; dh < 2; dh++)
                oacc[dh] = __builtin_amdgcn_mfma_f32_32x32x16_bf16(afr, vf[c][dh], oacc[dh], 0, 0, 0);
        }
    }

    // 4-way reduction via LDS
    if (ks) {
        float* rp = &red[ks - 1][0];
#pragma unroll
        for (int dh = 0; dh < 2; dh++)
#pragma unroll
            for (int r = 0; r < 16; r++) {
                int qloc = (r & 3) + 8 * (r >> 2) + 4 * hi;
                rp[qloc * 64 + dh * 32 + ln] = oacc[dh][r];
            }
    }
    __syncthreads();
    if (ks == 0) {
        const int b = g >> 3, h = g & 7;
        float sm = 0.f, sq = 0.f;
#pragma unroll
        for (int dh = 0; dh < 2; dh++)
#pragma unroll
            for (int r = 0; r < 16; r++) {
                int qloc = (r & 3) + 8 * (r >> 2) + 4 * hi;
                int col = qloc * 64 + dh * 32 + ln;
                float v = oacc[dh][r] + red[0][col] + red[1][col] + red[2][col];
                int q = q0 + qloc;
                out[((size_t)(b * T_ + q)) * D_ + h * 64 + dh * 32 + ln] = v;
                sm += v; sq += v * v;
            }
        for (int off = 32; off > 0; off >>= 1) {
            sm += __shfl_down(sm, off);
            sq += __shfl_down(sq, off);
        }
        if (lane == 0) {
            atomicAdd(&stats[g], sm);
            atomicAdd(&stats[NG_ + g], sq);
        }
    }
}

// ---------------- Kernel 3: GroupNorm epilogue (in place) ----------------
__global__ __launch_bounds__(256) void norm_kernel(
    float* __restrict__ out, const float* __restrict__ stats,
    const float* __restrict__ gn_w, const float* __restrict__ gn_b)
{
    int idx = blockIdx.x * 256 + threadIdx.x;
    if (idx >= B_ * T_ * D_) return;
    int c = idx & (D_ - 1);
    int b = idx >> 20;
    int g = b * H_ + (c >> 6);
    const float invN = 1.f / (float)(T_ * HD_);
    float mean = stats[g] * invN;
    float var  = stats[NG_ + g] * invN - mean * mean;
    float inv  = rsqrtf(var + EPS_);
    out[idx] = (out[idx] - mean) * inv * gn_w[c] + gn_b[c];
}

extern "C" void kernel_launch(void* const* d_in, const int* in_sizes, int n_in,
                              void* d_out, int out_size, void* d_ws, size_t ws_size,
                              hipStream_t stream)
{
    const float* x    = (const float*)d_in[0];
    const float* Wq   = (const float*)d_in[1];
    const float* bq   = (const float*)d_in[2];
    const float* Wk   = (const float*)d_in[3];
    const float* bk   = (const float*)d_in[4];
    const float* Wv   = (const float*)d_in[5];
    const float* bv   = (const float*)d_in[6];
    const float* gn_w = (const float*)d_in[7];
    const float* gn_b = (const float*)d_in[8];
    const float* gam  = (const float*)d_in[9];
    float* out = (float*)d_out;

    const size_t per = (size_t)B_ * H_ * T_ * HD_;   // 2M elements
    float* stats = (float*)d_ws;
    short* Qw  = (short*)((char*)d_ws + 256);
    short* Kw  = Qw + per;
    short* Vtw = Kw + per;
    short* xb  = Vtw + per;
    short* Wb  = xb + per;                            // 3*512*512 shorts

    hipMemsetAsync(stats, 0, 256, stream);
    convert_kernel<<<1408, 256, 0, stream>>>(x, Wq, Wk, Wv, xb, Wb);
    proj_mfma<<<dim3(64, 4, 3), 256, 0, stream>>>(xb, Wb, bq, bk, bv, Qw, Kw, Vtw);
    retention_kernel<<<dim3(64, 16), 256, 0, stream>>>(Qw, Kw, Vtw, gam, out, stats);
    norm_kernel<<<8192, 256, 0, stream>>>(out, stats, gn_w, gn_b);
}

// Round 6
// 128.047 us; speedup vs baseline: 5.0795x; 1.0871x over previous
//
#include <hip/hip_runtime.h>
#include <math.h>

#define B_ 2
#define T_ 2048
#define D_ 512
#define H_ 8
#define HD_ 64
#define NG_ (B_*H_)
#define EPS_ 1e-5f

typedef __attribute__((ext_vector_type(8)))  short  short8;   // 8 bf16 (4 VGPRs)
typedef __attribute__((ext_vector_type(16))) float  floatx16; // MFMA 32x32 acc

__device__ inline floatx16 zero16() {
    floatx16 z;
#pragma unroll
    for (int i = 0; i < 16; i++) z[i] = 0.f;
    return z;
}

// round-to-nearest-even fp32 -> bf16
__device__ inline unsigned pack2bf(float a, float b) {
    unsigned ua = __float_as_uint(a), ub = __float_as_uint(b);
    ua = (ua + 0x7fffu + ((ua >> 16) & 1u)) >> 16;
    ub = (ub + 0x7fffu + ((ub >> 16) & 1u)) >> 16;
    return ua | (ub << 16);
}
__device__ inline short bf1(float a) {
    unsigned ua = __float_as_uint(a);
    return (short)((ua + 0x7fffu + ((ua >> 16) & 1u)) >> 16);
}

// ---------------- Kernel 0: fp32 -> bf16 convert (x and Wq|Wk|Wv) ----------
__global__ __launch_bounds__(256) void convert_kernel(
    const float* __restrict__ x,
    const float* __restrict__ Wq, const float* __restrict__ Wk, const float* __restrict__ Wv,
    short* __restrict__ xb, short* __restrict__ Wb)
{
    const int XN = 4096 * 512;       // 2M
    const int WN = 512 * 512;        // 256K
    size_t e = ((size_t)blockIdx.x * 256 + threadIdx.x) * 8;
    const float* src; short* dst;
    if (e < XN)               { src = x  + e;               dst = xb + e; }
    else if (e < XN + WN)     { src = Wq + (e - XN);        dst = Wb + (e - XN); }
    else if (e < XN + 2*WN)   { src = Wk + (e - XN - WN);   dst = Wb + (e - XN); }
    else                      { src = Wv + (e - XN - 2*WN); dst = Wb + (e - XN); }
    float4 a = *(const float4*)src;
    float4 b = *(const float4*)(src + 4);
    uint4 o;
    o.x = pack2bf(a.x, a.y); o.y = pack2bf(a.z, a.w);
    o.z = pack2bf(b.x, b.y); o.w = pack2bf(b.z, b.w);
    *(uint4*)dst = o;
}

// ---------------- Kernel 1: QKV projection via MFMA bf16, double-buffered --
// C = x @ W^T + b. 64x128 tile/block, 4 waves each 32m x 64n.
// LDS 2x24KB -> 3 blocks/CU; stage k+1 overlaps compute k (1 barrier/step).
// Q,K -> [g][t][64] (lane = channel); V -> Vt[g][d][2048] (lane = token).
__global__ __launch_bounds__(256) void proj_mfma(
    const short* __restrict__ xb, const short* __restrict__ Wb,
    const float* __restrict__ bq, const float* __restrict__ bk, const float* __restrict__ bv,
    short* __restrict__ Qo, short* __restrict__ Ko, short* __restrict__ Vto)
{
    __shared__ short Xs[2][64 * 64];    // [buf][token][k]  2x8 KB
    __shared__ short Ws2[2][128 * 64];  // [buf][chan][k]   2x16 KB

    const int tid = threadIdx.x;
    const int w = tid >> 6, lane = tid & 63;
    const int hi = lane >> 5, ln = lane & 31;
    const int mt0 = blockIdx.x * 64;
    const int nt0 = blockIdx.y * 128;
    const int z = blockIdx.z;
    const bool isV = (z == 2);
    const float* bias = (z == 0) ? bq : (z == 1) ? bk : bv;
    const short* Wz = Wb + (size_t)z * 512 * 512;

    const int srow = tid >> 3;       // 0..31
    const int scol = (tid & 7) * 8;  // shorts
    const int mh = w & 1, nh = w >> 1;

    floatx16 acc[2] = {zero16(), zero16()};

    auto stage = [&](int b, int k0) {
#pragma unroll
        for (int i = 0; i < 2; i++) {
            const short* gx = xb + (size_t)(mt0 + srow + i * 32) * 512 + k0 + scol;
            short* lx = &Xs[b][(srow + i * 32) * 64 + scol];
            __builtin_amdgcn_global_load_lds(
                (const __attribute__((address_space(1))) unsigned*)gx,
                (__attribute__((address_space(3))) unsigned*)lx, 16, 0, 0);
        }
#pragma unroll
        for (int i = 0; i < 4; i++) {
            const short* gw = Wz + (size_t)(nt0 + srow + i * 32) * 512 + k0 + scol;
            short* lw = &Ws2[b][(srow + i * 32) * 64 + scol];
            __builtin_amdgcn_global_load_lds(
                (const __attribute__((address_space(1))) unsigned*)gw,
                (__attribute__((address_space(3))) unsigned*)lw, 16, 0, 0);
        }
    };

    stage(0, 0);
    int buf = 0;
    for (int k0 = 0; k0 < 512; k0 += 64, buf ^= 1) {
        __syncthreads();                       // buf ready (barrier drains vmcnt)
        if (k0 + 64 < 512) stage(buf ^ 1, k0 + 64);   // async fill of other buf
#pragma unroll
        for (int kk = 0; kk < 4; kk++) {
            short8 xf = *(const short8*)(&Xs[buf][(mh * 32 + ln) * 64 + kk * 16 + hi * 8]);
            short8 wf[2];
#pragma unroll
            for (int s = 0; s < 2; s++)
                wf[s] = *(const short8*)(&Ws2[buf][(nh * 64 + s * 32 + ln) * 64 + kk * 16 + hi * 8]);
#pragma unroll
            for (int b = 0; b < 2; b++)
                acc[b] = isV
                    ? __builtin_amdgcn_mfma_f32_32x32x16_bf16(wf[b], xf, acc[b], 0, 0, 0)
                    : __builtin_amdgcn_mfma_f32_32x32x16_bf16(xf, wf[b], acc[b], 0, 0, 0);
        }
    }

    const int head = blockIdx.y * 2 + nh;

    if (!isV) {
        short* dst = (z == 0) ? Qo : Ko;
        float bias_v[2];
#pragma unroll
        for (int b = 0; b < 2; b++) bias_v[b] = bias[nt0 + nh * 64 + b * 32 + ln];
#pragma unroll
        for (int r = 0; r < 16; r++) {
            int m = mt0 + mh * 32 + (r & 3) + 8 * (r >> 2) + 4 * hi;
            int batch = m >> 11, t = m & (T_ - 1);
            size_t rowb = ((size_t)(batch * H_ + head) * T_ + t) * HD_;
#pragma unroll
            for (int b = 0; b < 2; b++)
                dst[rowb + b * 32 + ln] = bf1(acc[b][r] + bias_v[b]);
        }
    } else {
        const int m = mt0 + mh * 32 + ln;
        const int batch = m >> 11, t = m & (T_ - 1);
#pragma unroll
        for (int b = 0; b < 2; b++) {
#pragma unroll
            for (int r = 0; r < 16; r++) {
                int chan = nt0 + nh * 64 + b * 32 + (r & 3) + 8 * (r >> 2) + 4 * hi;
                int d = chan & (HD_ - 1);
                Vto[((size_t)(batch * H_ + head) * HD_ + d) * T_ + t] = bf1(acc[b][r] + bias[chan]);
            }
        }
    }
}

// ---------------- Kernel 2: windowed retention, MFMA bf16, XCD-pinned ------
// grid (16 groups, 64 q-tiles of 32): linear wg%8 = g%8 pins each group's
// K/Vt to one XCD's L2. 4 waves = k-parity 0..3; next-K prefetch in-loop.
__global__ __launch_bounds__(256, 2) void retention_kernel(
    const short* __restrict__ Q, const short* __restrict__ K, const short* __restrict__ Vt,
    const float* __restrict__ gamma_p,
    float* __restrict__ out,     // [B,T,D] pre-norm fp32
    float* __restrict__ stats)   // [16 sums][16 sumsq]
{
    __shared__ float red[3][32 * 64];   // partials from waves 1..3, 24 KB

    const int tid  = threadIdx.x;
    const int ks   = tid >> 6, lane = tid & 63;
    const int hi   = lane >> 5, ln = lane & 31;
    const int g    = blockIdx.x, qtt = blockIdx.y;   // x=g -> XCD = g%8
    const int q0   = qtt * 32;          // global query base
    const int qt   = qtt >> 1;          // 64-wide ktile index containing q0

    const float gamma = gamma_p[0];
    const float lg = logf(gamma);
    int kt0 = 0;
    if (lg < -1e-6f) {
        int maxd = (int)(-34.0f / lg) + 64;   // gamma^maxd < ~2e-15
        kt0 = qt - (maxd >> 6);
        if (kt0 < 0) kt0 = 0;
    }

    // Q fragments (B-operand of S^T = K*Q^T): col q = ln
    const short* Qbase = Q + ((size_t)g * T_ + q0 + ln) * HD_;
    short8 qf[4];
#pragma unroll
    for (int c = 0; c < 4; c++) qf[c] = *(const short8*)(Qbase + 16 * c + 8 * hi);

    // decay: gamma^(q-k) = Alane * Ckt * G32^kh * Ea[r&3]*Eb[r>>2]
    const float Alane = __expf(lg * (float)(ln - 4 * hi));
    const float G32   = __expf(-lg * 32.0f);
    float Ea[4], Eb[4];
#pragma unroll
    for (int j = 0; j < 4; j++) { Ea[j] = __expf(-lg * (float)j); Eb[j] = __expf(-lg * (float)(8 * j)); }
    const int qrel = (qtt & 1) * 32 + ln;   // q within its 64-ktile

    floatx16 oacc[2] = {zero16(), zero16()};

    int kt = kt0 + ((ks - kt0) & 3);
    short8 kf[2][4];
    if (kt <= qt) {
        const short* Kbase = K + ((size_t)g * T_ + kt * 64) * HD_;
#pragma unroll
        for (int kh = 0; kh < 2; kh++)
#pragma unroll
            for (int c = 0; c < 4; c++)
                kf[kh][c] = *(const short8*)(Kbase + (size_t)(kh * 32 + ln) * HD_ + 16 * c + 8 * hi);
    }

    for (; kt <= qt; kt += 4) {
        const int k0 = kt * 64;

        // S^T quadrants from prefetched K: A = K rows, B = Q cols
        floatx16 st[2];
#pragma unroll
        for (int kh = 0; kh < 2; kh++) {
            floatx16 acc = zero16();
#pragma unroll
            for (int c = 0; c < 4; c++)
                acc = __builtin_amdgcn_mfma_f32_32x32x16_bf16(kf[kh][c], qf[c], acc, 0, 0, 0);
            st[kh] = acc;
        }

        // V fragments for this ktile (in flight during decay+pack)
        short8 vf[4][2];
#pragma unroll
        for (int c = 0; c < 4; c++)
#pragma unroll
            for (int dh = 0; dh < 2; dh++)
                vf[c][dh] = *(const short8*)(Vt + ((size_t)g * HD_ + dh * 32 + ln) * T_ + k0 + 16 * c + 8 * hi);

        // prefetch next ktile's K fragments (st already holds S)
        const int ktn = kt + 4;
        if (ktn <= qt) {
            const short* Kn = K + ((size_t)g * T_ + ktn * 64) * HD_;
#pragma unroll
            for (int kh = 0; kh < 2; kh++)
#pragma unroll
                for (int c = 0; c < 4; c++)
                    kf[kh][c] = *(const short8*)(Kn + (size_t)(kh * 32 + ln) * HD_ + 16 * c + 8 * hi);
        }

        const float Ckt = __expf(lg * (float)(q0 - k0));
        const float base0 = Alane * Ckt;
        const bool diag = (kt == qt);
#pragma unroll
        for (int kh = 0; kh < 2; kh++) {
            float bb = base0 * (kh ? G32 : 1.0f);
#pragma unroll
            for (int r = 0; r < 16; r++) {
                float v = st[kh][r] * (bb * Ea[r & 3] * Eb[r >> 2]);
                if (diag) {
                    int kloc = kh * 32 + (r & 3) + 8 * (r >> 2) + 4 * hi;
                    if (qrel < kloc) v = 0.f;
                }
                st[kh][r] = v;
            }
        }

        // PV: O[q][d] += S[q][k] * V[k][d]
#pragma unroll
        for (int c = 0; c < 4; c++) {
            const int kh = c >> 1, rb = 8 * (c & 1);
            unsigned p0 = pack2bf(st[kh][rb+0], st[kh][rb+1]);
            unsigned p1 = pack2bf(st[kh][rb+2], st[kh][rb+3]);
            unsigned p2 = pack2bf(st[kh][rb+4], st[kh][rb+5]);
            unsigned p3 = pack2bf(st[kh][rb+6], st[kh][rb+7]);
            unsigned t0s = (unsigned)__shfl_xor((int)(hi ? p0 : p2), 32, 64);
            unsigned t1s = (unsigned)__shfl_xor((int)(hi ? p1 : p3), 32, 64);
            uint4 aw;
            aw.x = hi ? t0s : p0;  aw.y = hi ? t1s : p1;
            aw.z = hi ? p2  : t0s; aw.w = hi ? p3  : t1s;
            short8 afr = *reinterpret_cast<short8*>(&aw);
#pragma unroll
            for (int dh = 0; dh < 2; dh++)
                oacc[dh] = __builtin_amdgcn_mfma_f32_32x32x16_bf16(afr, vf[c][dh], oacc[dh], 0, 0, 0);
        }
    }

    // 4-way reduction via LDS
    if (ks) {
        float* rp = &red[ks - 1][0];
#pragma unroll
        for (int dh = 0; dh < 2; dh++)
#pragma unroll
            for (int r = 0; r < 16; r++) {
                int qloc = (r & 3) + 8 * (r >> 2) + 4 * hi;
                rp[qloc * 64 + dh * 32 + ln] = oacc[dh][r];
            }
    }
    __syncthreads();
    if (ks == 0) {
        const int b = g >> 3, h = g & 7;
        float sm = 0.f, sq = 0.f;
#pragma unroll
        for (int dh = 0; dh < 2; dh++)
#pragma unroll
            for (int r = 0; r < 16; r++) {
                int qloc = (r & 3) + 8 * (r >> 2) + 4 * hi;
                int col = qloc * 64 + dh * 32 + ln;
                float v = oacc[dh][r] + red[0][col] + red[1][col] + red[2][col];
                int q = q0 + qloc;
                out[((size_t)(b * T_ + q)) * D_ + h * 64 + dh * 32 + ln] = v;
                sm += v; sq += v * v;
            }
        for (int off = 32; off > 0; off >>= 1) {
            sm += __shfl_down(sm, off);
            sq += __shfl_down(sq, off);
        }
        if (lane == 0) {
            atomicAdd(&stats[g], sm);
            atomicAdd(&stats[NG_ + g], sq);
        }
    }
}

// ---------------- Kernel 3: GroupNorm epilogue (in place, float4) ----------
__global__ __launch_bounds__(256) void norm_kernel(
    float* __restrict__ out, const float* __restrict__ stats,
    const float* __restrict__ gn_w, const float* __restrict__ gn_b)
{
    int idx4 = blockIdx.x * 256 + threadIdx.x;
    if (idx4 >= (B_ * T_ * D_) / 4) return;
    int base = idx4 * 4;
    int c0 = base & (D_ - 1);
    int b = base >> 20;                 // T_*D_ = 2^20
    int g = b * H_ + (c0 >> 6);
    const float invN = 1.f / (float)(T_ * HD_);
    float mean = stats[g] * invN;
    float var  = stats[NG_ + g] * invN - mean * mean;
    float inv  = rsqrtf(var + EPS_);
    float4 v = *(float4*)&out[base];
    float4 wv = *(const float4*)&gn_w[c0];
    float4 bv = *(const float4*)&gn_b[c0];
    v.x = (v.x - mean) * inv * wv.x + bv.x;
    v.y = (v.y - mean) * inv * wv.y + bv.y;
    v.z = (v.z - mean) * inv * wv.z + bv.z;
    v.w = (v.w - mean) * inv * wv.w + bv.w;
    *(float4*)&out[base] = v;
}

extern "C" void kernel_launch(void* const* d_in, const int* in_sizes, int n_in,
                              void* d_out, int out_size, void* d_ws, size_t ws_size,
                              hipStream_t stream)
{
    const float* x    = (const float*)d_in[0];
    const float* Wq   = (const float*)d_in[1];
    const float* bq   = (const float*)d_in[2];
    const float* Wk   = (const float*)d_in[3];
    const float* bk   = (const float*)d_in[4];
    const float* Wv   = (const float*)d_in[5];
    const float* bv   = (const float*)d_in[6];
    const float* gn_w = (const float*)d_in[7];
    const float* gn_b = (const float*)d_in[8];
    const float* gam  = (const float*)d_in[9];
    float* out = (float*)d_out;

    const size_t per = (size_t)B_ * H_ * T_ * HD_;   // 2M elements
    float* stats = (float*)d_ws;
    short* Qw  = (short*)((char*)d_ws + 256);
    short* Kw  = Qw + per;
    short* Vtw = Kw + per;
    short* xb  = Vtw + per;
    short* Wb  = xb + per;                            // 3*512*512 shorts

    hipMemsetAsync(stats, 0, 256, stream);
    convert_kernel<<<1408, 256, 0, stream>>>(x, Wq, Wk, Wv, xb, Wb);
    proj_mfma<<<dim3(64, 4, 3), 256, 0, stream>>>(xb, Wb, bq, bk, bv, Qw, Kw, Vtw);
    retention_kernel<<<dim3(16, 64), 256, 0, stream>>>(Qw, Kw, Vtw, gam, out, stats);
    norm_kernel<<<2048, 256, 0, stream>>>(out, stats, gn_w, gn_b);   // 2M elems / 4 per thread / 256
}